// Round 12
// baseline (960.915 us; speedup 1.0000x reference)
//
#include <hip/hip_runtime.h>
#include <hip/hip_cooperative_groups.h>

namespace cg = cooperative_groups;

// Problem dims
#define B_  32
#define N_  1024
#define E_  1024
#define H_  8
#define D_  128
#define MID_ 64
#define NT_  32        // n-tiles for score+pool (32 rows each)
#define TR_  32        // rows per tile

// Journal (counter-backed lessons):
//  R3:  never replay a stream. R4: never scale same-dest atomic writers.
//  R5/R6: VGPR=64 cap on (X,4) launch_bounds = spill; use plain bounds.
//  R7:  scorepool 92us / VGPR 72 / bytes ideal. BEST total 372.
//  R9:  run live-set arithmetic BEFORE benching. R10: score||pool
//       interleave in one 256-thr kernel degrades both.
//  R11: batching weights (380->36 MB logical) did NOT move the ~280us
//       residual; residual is invariant to kernel count AND hidden-kernel
//       workload => serial dispatch-chain overhead (launch+drain+gap).
//  R12: ONE cooperative kernel (256 blk x 1024 thr, 1 blk/CU co-resident),
//       6 phases with grid.sync(); 2 dispatches total. k_main phase keeps
//       R7's inner loop verbatim at the same 16 waves/CU.

__device__ __forceinline__ float dot4(float4 a, float4 b) {
    return a.x * b.x + a.y * b.y + a.z * b.z + a.w * b.w;
}

union SMem {
    struct { float qsh[8 * E_]; float Qrow[8][16]; } q;        // 33 KB
    struct { int rows[4][32]; int nrows[4]; } pool;            // 0.5 KB
    struct { float QsL[32 * 132]; float WkL[128 * 32]; } kk;   // 33 KB
    struct { float part[4][4][4][8]; float sfin[4][4][8]; } mn;// 2.5 KB
    struct { float4 red[4][256]; } rd;                         // 16 KB
    struct { float pL[8 * E_]; float p2L[8 * E_]; } at;        // 64 KB
    struct { float att[D_]; float hv[MID_]; float red2[2]; float cnt; } fin;
};

__global__ __launch_bounds__(1024) void k_mega(
        const float* __restrict__ query, const float* __restrict__ Wq,
        const float* __restrict__ bq, const float* __restrict__ Wk,
        const float* __restrict__ bk, const float* __restrict__ key,
        const float* __restrict__ value2, const int* __restrict__ mask,
        const float* __restrict__ Wv, const float* __restrict__ bv,
        const float* __restrict__ Wb, const float* __restrict__ bbias,
        const float* __restrict__ Wl2, const float* __restrict__ bl2,
        const float* __restrict__ value1,
        float* __restrict__ Qs, float* __restrict__ qb,
        float* __restrict__ qk, float* __restrict__ PPpart,
        float* __restrict__ ssum, float* __restrict__ P2p,
        float* __restrict__ pooled, float* __restrict__ pool2,
        float* __restrict__ attA, float* __restrict__ attV,
        float* __restrict__ out)
{
    cg::grid_group grid = cg::this_grid();
    __shared__ SMem sm;
    const int bid = blockIdx.x;
    const int t = threadIdx.x;
    const int g = t >> 8, tg = t & 255;     // 4 groups of 256 threads

    // ================= P0a: v2 pooling (4 jobs/block, all 1024 jobs) ======
    {
        const int job = bid * 4 + g;
        const int b = job & 31, sp = job >> 5;   // 32 splits of 32 rows
        const int n0 = sp * 32;
        if (tg == 0) sm.pool.nrows[g] = 0;
        __syncthreads();
        if (tg < 32) {
            if (mask[b * N_ + n0 + tg]) {
                int i2 = atomicAdd(&sm.pool.nrows[g], 1);
                sm.pool.rows[g][i2] = tg;
            }
        }
        __syncthreads();
        const int nr = sm.pool.nrows[g];
        const int e0 = tg * 4;
        float a0 = 0.f, a1 = 0.f, a2 = 0.f, a3 = 0.f;
        const float* vb = value2 + ((size_t)(b * N_ + n0)) * E_ + e0;
        #pragma unroll 4
        for (int i = 0; i < nr; ++i) {
            float4 v = *(const float4*)(vb + (size_t)sm.pool.rows[g][i] * E_);
            a0 += v.x; a1 += v.y; a2 += v.z; a3 += v.w;
        }
        float* dst = P2p + ((size_t)(sp & 7) * B_ + b) * E_ + e0;
        atomicAdd(dst + 0, a0); atomicAdd(dst + 1, a1);
        atomicAdd(dst + 2, a2); atomicAdd(dst + 3, a3);
    }
    __syncthreads();   // pool's rows[] dead; union reused by qsh below

    // ================= P0b: Qs tile (1 job/block: 8 b x 16 Wq rows) =======
    {
        const int bg = bid >> 6, rs = bid & 63;
        const int b0 = bg * 8, R = rs * 16, h = rs >> 3;
        {
            const int bb = t >> 7, ln = t & 127;
            const float4* src = (const float4*)(query + (size_t)(b0 + bb) * E_);
            float4* dst = (float4*)(sm.q.qsh + bb * E_);
            dst[ln] = src[ln];
            dst[ln + 128] = src[ln + 128];
        }
        __syncthreads();
        const int r = t >> 6, cl = t & 63;
        const int row = R + r;
        const float4* wr = (const float4*)(Wq + (size_t)row * E_);
        const float4 w0 = wr[cl], w1 = wr[cl + 64],
                     w2 = wr[cl + 128], w3 = wr[cl + 192];
        const float4* qsh4 = (const float4*)sm.q.qsh;
        const float bqv = bq[row];
        #pragma unroll
        for (int bb = 0; bb < 8; ++bb) {
            float acc = dot4(w0, qsh4[bb * 256 + cl])
                      + dot4(w1, qsh4[bb * 256 + cl + 64])
                      + dot4(w2, qsh4[bb * 256 + cl + 128])
                      + dot4(w3, qsh4[bb * 256 + cl + 192]);
            #pragma unroll
            for (int off = 32; off; off >>= 1) acc += __shfl_xor(acc, off);
            if (cl == 0) sm.q.Qrow[bb][r] = acc + bqv;
        }
        __syncthreads();
        if (t < 8) {
            float s = 0.f;
            #pragma unroll
            for (int rr = 0; rr < 16; ++rr) s += sm.q.Qrow[t][rr] * bk[R + rr];
            atomicAdd(&qb[(b0 + t) * 8 + h], s);
        }
        if (t < 32) {
            const int bb = t >> 2, j = t & 3;
            ((float4*)(Qs + (size_t)(b0 + bb) * E_))[rs * 4 + j] =
                *(const float4*)&sm.q.Qrow[bb][j * 4];
        }
    }
    __threadfence();
    grid.sync();

    // ================= P1: qk = Qs_h @ Wk_h (LDS-tiled GEMM) ==============
    {
        const int h = bid >> 5, ec = bid & 31;
        {
            const int b = t >> 5, j = t & 31;
            ((float4*)(sm.kk.QsL + b * 132))[j] =
                ((const float4*)(Qs + (size_t)b * E_))[h * 32 + j];
        }
        {
            const int d = t >> 3, c = t & 7;
            ((float4*)sm.kk.WkL)[t] =
                ((const float4*)(Wk + (size_t)(h * D_ + d) * E_))[ec * 8 + c];
        }
        __syncthreads();
        const int b = t >> 5, ef = t & 31;
        float acc = 0.f;
        const float* qrow = sm.kk.QsL + b * 132;
        #pragma unroll 8
        for (int d = 0; d < D_; ++d)
            acc += qrow[d] * sm.kk.WkL[d * 32 + ef];
        qk[(size_t)(b * 8 + h) * E_ + ec * 32 + ef] = acc;
    }
    __threadfence();
    grid.sync();

    // ================= P2: score+pool (R7 k_main verbatim, per group) =====
    {
        const int j = bid * 4 + g;
        const int b = j >> 5, tile = j & 31;
        const int w = tg >> 6, l = tg & 63;
        const float scale = 0.08838834764831845f;  // 1/sqrt(128)
        const float* keyb = key + ((size_t)b * N_ + (size_t)tile * TR_) * E_;
        const float qbv = (tg < 32) ? qb[b * 8 + (tg & 7)] : 0.f;

        float4 qkr[8];
        #pragma unroll
        for (int h = 0; h < H_; ++h)
            qkr[h] = ((const float4*)(qk + (size_t)(b * 8 + h) * E_))[tg];

        float4 pacc[8];
        #pragma unroll
        for (int h = 0; h < 8; ++h) pacc[h] = make_float4(0.f, 0.f, 0.f, 0.f);

        float ts = 0.f;
        float4 kv[4];
        #pragma unroll
        for (int r = 0; r < 4; ++r)
            kv[r] = ((const float4*)(keyb + (size_t)r * E_))[tg];

        for (int st = 0; st < 8; ++st) {
            #pragma unroll
            for (int r = 0; r < 4; ++r) {
                float p[8];
                #pragma unroll
                for (int h = 0; h < 8; ++h) p[h] = dot4(qkr[h], kv[r]);
                #pragma unroll
                for (int off = 32; off; off >>= 1) {
                    #pragma unroll
                    for (int h = 0; h < 8; ++h)
                        p[h] += __shfl_xor(p[h], off);
                }
                if (l == 0) {
                    *(float4*)&sm.mn.part[g][w][r][0] =
                        make_float4(p[0], p[1], p[2], p[3]);
                    *(float4*)&sm.mn.part[g][w][r][4] =
                        make_float4(p[4], p[5], p[6], p[7]);
                }
            }
            float4 kn[4];
            if (st < 7) {
                #pragma unroll
                for (int r = 0; r < 4; ++r)
                    kn[r] = ((const float4*)(keyb
                                + (size_t)((st + 1) * 4 + r) * E_))[tg];
            }
            __syncthreads();
            if (tg < 32) {
                const int r = tg >> 3, h = tg & 7;
                float s = (sm.mn.part[g][0][r][h] + sm.mn.part[g][1][r][h]
                         + sm.mn.part[g][2][r][h] + sm.mn.part[g][3][r][h]
                         + qbv) * scale;
                sm.mn.sfin[g][r][h] = s;
                ts += s;
            }
            __syncthreads();
            #pragma unroll
            for (int r = 0; r < 4; ++r) {
                const float4 k4 = kv[r];
                const float4 sA = *(const float4*)&sm.mn.sfin[g][r][0];
                const float4 sB = *(const float4*)&sm.mn.sfin[g][r][4];
                pacc[0].x += sA.x * k4.x; pacc[0].y += sA.x * k4.y;
                pacc[0].z += sA.x * k4.z; pacc[0].w += sA.x * k4.w;
                pacc[1].x += sA.y * k4.x; pacc[1].y += sA.y * k4.y;
                pacc[1].z += sA.y * k4.z; pacc[1].w += sA.y * k4.w;
                pacc[2].x += sA.z * k4.x; pacc[2].y += sA.z * k4.y;
                pacc[2].z += sA.z * k4.z; pacc[2].w += sA.z * k4.w;
                pacc[3].x += sA.w * k4.x; pacc[3].y += sA.w * k4.y;
                pacc[3].z += sA.w * k4.z; pacc[3].w += sA.w * k4.w;
                pacc[4].x += sB.x * k4.x; pacc[4].y += sB.x * k4.y;
                pacc[4].z += sB.x * k4.z; pacc[4].w += sB.x * k4.w;
                pacc[5].x += sB.y * k4.x; pacc[5].y += sB.y * k4.y;
                pacc[5].z += sB.y * k4.z; pacc[5].w += sB.y * k4.w;
                pacc[6].x += sB.z * k4.x; pacc[6].y += sB.z * k4.y;
                pacc[6].z += sB.z * k4.z; pacc[6].w += sB.z * k4.w;
                pacc[7].x += sB.w * k4.x; pacc[7].y += sB.w * k4.y;
                pacc[7].z += sB.w * k4.z; pacc[7].w += sB.w * k4.w;
            }
            #pragma unroll
            for (int r = 0; r < 4; ++r) kv[r] = kn[r];
        }

        if (tg < 32) {
            float v = ts;
            v += __shfl_xor(v, 8);
            v += __shfl_xor(v, 16);
            if (l < 8) atomicAdd(&ssum[b * 8 + l], v);
        }
        #pragma unroll
        for (int h = 0; h < 8; ++h) {
            ((float4*)(PPpart
                + (((size_t)(b * H_ + h)) * NT_ + tile) * E_))[tg] = pacc[h];
        }
    }
    __threadfence();
    grid.sync();

    // ================= P3: reduce PPpart -> pooled; fold P2p -> pool2 =====
    {
        const int bh = bid;
        const float4* pp = (const float4*)(PPpart + (size_t)bh * NT_ * E_);
        float4 s = make_float4(0.f, 0.f, 0.f, 0.f);
        #pragma unroll
        for (int jj = 0; jj < 8; ++jj) {
            float4 v = pp[(g * 8 + jj) * 256 + tg];
            s.x += v.x; s.y += v.y; s.z += v.z; s.w += v.w;
        }
        sm.rd.red[g][tg] = s;
        __syncthreads();
        if (t < 256) {
            float4 r0 = sm.rd.red[0][t], r1 = sm.rd.red[1][t];
            float4 r2 = sm.rd.red[2][t], r3 = sm.rd.red[3][t];
            ((float4*)(pooled + (size_t)bh * E_))[t] =
                make_float4(r0.x + r1.x + r2.x + r3.x,
                            r0.y + r1.y + r2.y + r3.y,
                            r0.z + r1.z + r2.z + r3.z,
                            r0.w + r1.w + r2.w + r3.w);
        }
        if (bid < B_ && t < 256) {
            float4 q = make_float4(0.f, 0.f, 0.f, 0.f);
            #pragma unroll
            for (int k2 = 0; k2 < 8; ++k2) {
                float4 v = ((const float4*)(P2p
                                + ((size_t)k2 * B_ + bid) * E_))[t];
                q.x += v.x; q.y += v.y; q.z += v.z; q.w += v.w;
            }
            ((float4*)(pool2 + (size_t)bid * E_))[t] = q;
        }
    }
    __threadfence();
    grid.sync();

    // ================= P4: Wv dots, batched 8 b's per block ===============
    {
        const int h = bid >> 5, dc = (bid >> 2) & 7, bq4 = bid & 3;
        const int b0 = bq4 * 8;
        {
            const int bb = t >> 7, ln = t & 127;
            const float4* sp = (const float4*)(pooled
                                + (size_t)((b0 + bb) * 8 + h) * E_);
            const float4* s2 = (const float4*)(pool2 + (size_t)(b0 + bb) * E_);
            float4* dp = (float4*)(sm.at.pL + bb * E_);
            float4* d2 = (float4*)(sm.at.p2L + bb * E_);
            dp[ln] = sp[ln]; dp[ln + 128] = sp[ln + 128];
            d2[ln] = s2[ln]; d2[ln + 128] = s2[ln + 128];
        }
        __syncthreads();
        const int r = t >> 6, cl = t & 63;
        const int d = dc * 16 + r;
        const float4* wvr = (const float4*)(Wv + (size_t)(h * D_ + d) * E_);
        const float4 w0 = wvr[cl], w1 = wvr[cl + 64],
                     w2 = wvr[cl + 128], w3 = wvr[cl + 192];
        const float4* pL4 = (const float4*)sm.at.pL;
        const float4* p2L4 = (const float4*)sm.at.p2L;
        float aA[8], aV[8];
        #pragma unroll
        for (int bb = 0; bb < 8; ++bb) {
            aA[bb] = dot4(w0, pL4[bb * 256 + cl])
                   + dot4(w1, pL4[bb * 256 + cl + 64])
                   + dot4(w2, pL4[bb * 256 + cl + 128])
                   + dot4(w3, pL4[bb * 256 + cl + 192]);
            aV[bb] = dot4(w0, p2L4[bb * 256 + cl])
                   + dot4(w1, p2L4[bb * 256 + cl + 64])
                   + dot4(w2, p2L4[bb * 256 + cl + 128])
                   + dot4(w3, p2L4[bb * 256 + cl + 192]);
        }
        #pragma unroll
        for (int off = 32; off; off >>= 1) {
            #pragma unroll
            for (int bb = 0; bb < 8; ++bb) {
                aA[bb] += __shfl_xor(aA[bb], off);
                aV[bb] += __shfl_xor(aV[bb], off);
            }
        }
        if (cl == 0) {
            #pragma unroll
            for (int bb = 0; bb < 8; ++bb) {
                const int bh2 = (b0 + bb) * 8 + h;
                attA[(size_t)bh2 * D_ + d] = aA[bb];
                attV[(size_t)bh2 * D_ + d] = aV[bb];
            }
        }
    }
    __threadfence();
    grid.sync();

    // ================= P5: epilogue =======================================
    {
        const int bh = bid, b = bh >> 3, h = bh & 7;
        if (t < 128) {
            int ci = 0;
            #pragma unroll
            for (int i = 0; i < 8; ++i) ci += mask[b * N_ + t + i * 128];
            float cf = (float)ci;
            #pragma unroll
            for (int off = 32; off; off >>= 1) cf += __shfl_down(cf, off);
            if ((t & 63) == 0) sm.fin.red2[t >> 6] = cf;
            const float ss = ssum[bh];
            sm.fin.att[t] = attA[(size_t)bh * D_ + t] + ss * bv[h * D_ + t];
        }
        __syncthreads();
        if (t == 0) sm.fin.cnt = sm.fin.red2[0] + sm.fin.red2[1];
        if (t < MID_) {
            float a = bbias[t];
            #pragma unroll 4
            for (int d2 = 0; d2 < D_; ++d2)
                a += sm.fin.att[d2] * Wb[t * D_ + d2];
            sm.fin.hv[t] = fmaxf(a, 0.f);
        }
        __syncthreads();
        if (t < 128) {
            float z = bl2[t];
            #pragma unroll
            for (int m = 0; m < MID_; ++m) z += sm.fin.hv[m] * Wl2[t * MID_ + m];
            float alphac = 1.f / (1.f + expf(-z));
            const float bvd = bv[h * D_ + t];
            float v2a = attV[(size_t)bh * D_ + t] / sm.fin.cnt + bvd;
            out[(size_t)b * E_ + h * D_ + t] =
                value1[(size_t)b * E_ + h * D_ + t] * v2a * alphac;
        }
    }
}

// ---------------------------------------------------------------------------
extern "C" void kernel_launch(void* const* d_in, const int* in_sizes, int n_in,
                              void* d_out, int out_size, void* d_ws, size_t ws_size,
                              hipStream_t stream)
{
    const float* query  = (const float*)d_in[0];
    const float* key    = (const float*)d_in[1];
    const int*   mask   = (const int*)d_in[2];
    const float* value1 = (const float*)d_in[3];
    const float* value2 = (const float*)d_in[4];
    const float* Wq  = (const float*)d_in[5];
    const float* bq  = (const float*)d_in[6];
    const float* Wk  = (const float*)d_in[7];
    const float* bk  = (const float*)d_in[8];
    const float* Wv  = (const float*)d_in[9];
    const float* bv  = (const float*)d_in[10];
    const float* Wb  = (const float*)d_in[11];
    const float* bbias = (const float*)d_in[12];
    // d_in[13] = Wl, d_in[14] = bl: eliminated (softmax of uniform = mask/cnt)
    const float* Wl2 = (const float*)d_in[15];
    const float* bl2 = (const float*)d_in[16];
    float* out = (float*)d_out;

    // workspace layout (bytes), ~36 MB
    char* ws = (char*)d_ws;
    const size_t SZ_PPP = (size_t)B_ * H_ * NT_ * E_ * 4;     // PPpart: 32 MB
    const size_t SZ_P2P = (size_t)8 * B_ * E_ * 4;            // P2p: 1 MB
    const size_t OFF_P2P = SZ_PPP;
    const size_t OFF_SS  = OFF_P2P + SZ_P2P;                  // ssum: 1 KB
    const size_t OFF_QB  = OFF_SS + 1024;                     // qb: 1 KB
    const size_t OFF_QS  = OFF_QB + 1024;                     // Qs: 128 KB
    const size_t OFF_QK  = OFF_QS + (size_t)B_ * E_ * 4;      // qk: 1 MB
    const size_t OFF_PL  = OFF_QK + (size_t)B_ * H_ * E_ * 4; // pooled: 1 MB
    const size_t OFF_P2  = OFF_PL + (size_t)B_ * H_ * E_ * 4; // pool2: 128 KB
    const size_t OFF_AA  = OFF_P2 + (size_t)B_ * E_ * 4;      // attA: 128 KB
    const size_t OFF_AV  = OFF_AA + (size_t)B_ * H_ * D_ * 4; // attV: 128 KB
    float* PPpart = (float*)(ws);
    float* P2p    = (float*)(ws + OFF_P2P);
    float* ssum   = (float*)(ws + OFF_SS);
    float* qb     = (float*)(ws + OFF_QB);
    float* Qs     = (float*)(ws + OFF_QS);
    float* qk     = (float*)(ws + OFF_QK);
    float* pooled = (float*)(ws + OFF_PL);
    float* pool2  = (float*)(ws + OFF_P2);
    float* attA   = (float*)(ws + OFF_AA);
    float* attV   = (float*)(ws + OFF_AV);

    // zero atomic-accumulated regions: P2p + ssum + qb (contiguous)
    hipMemsetAsync(ws + OFF_P2P, 0, SZ_P2P + 2048, stream);

    void* args[] = {
        (void*)&query, (void*)&Wq, (void*)&bq, (void*)&Wk, (void*)&bk,
        (void*)&key, (void*)&value2, (void*)&mask, (void*)&Wv, (void*)&bv,
        (void*)&Wb, (void*)&bbias, (void*)&Wl2, (void*)&bl2, (void*)&value1,
        (void*)&Qs, (void*)&qb, (void*)&qk, (void*)&PPpart, (void*)&ssum,
        (void*)&P2p, (void*)&pooled, (void*)&pool2, (void*)&attA,
        (void*)&attV, (void*)&out
    };
    hipLaunchCooperativeKernel((void*)k_mega, dim3(256), dim3(1024),
                               args, 0, stream);
}

// Round 13
// 369.972 us; speedup vs baseline: 2.5973x; 2.5973x over previous
//
#include <hip/hip_runtime.h>

// Problem dims
#define B_  32
#define N_  1024
#define E_  1024
#define H_  8
#define D_  128
#define MID_ 64
#define NT_  32        // n-tiles for score+pool (32 rows each)
#define TR_  32        // rows per tile
#define NSP_ 32        // v2-pool split rows

// Journal (counter-backed lessons):
//  R3:  never replay a stream. R4: never scale same-dest atomic writers.
//  R5/R6: VGPR=64 with bigger live-set = spill; plain launch_bounds only.
//  R7:  scorepool 92us / VGPR 72 / bytes ideal. Best total 372.
//  R9:  live-set arithmetic BEFORE benching. R10: score||pool interleave
//       degrades both. R11: weight batching (380->36 MB) moved NOTHING.
//  R12: 1024-thr mega-kernel -> allocator targets 2 blk/CU -> VGPR 64 cap
//       -> spill (WRITE 141 MB) + 1 blk/CU phases = 719us. Fusion dead end.
//  R13: __syncthreads() drains vmcnt(0) (guide §5) => k_main's 16 barriers
//       kill the kn prefetch every subtile. Replace in-loop barriers with
//       raw "s_waitcnt lgkmcnt(0); s_barrier" (LDS-only visibility — part/
//       sfin) so key loads stay in flight across barriers (HK T4 minimal).
//       Also: fuse tail to k_tail (R8-proven), 5 dispatches total.

// LDS-only barrier: does NOT drain vmcnt — global loads stay in flight.
__device__ __forceinline__ void ldsbar() {
    asm volatile("s_waitcnt lgkmcnt(0)\n"
                 "s_barrier" ::: "memory");
}

// ---------------------------------------------------------------------------
// k_q: blocks [0,256): Qs = query@Wq^T + bq (batched: 8 b x 16 rows/block);
//      blocks [256,1280): v2 pooling (independent stream, overlaps).
// ---------------------------------------------------------------------------
__global__ __launch_bounds__(256) void k_q(
        const float* __restrict__ query, const float* __restrict__ Wq,
        const float* __restrict__ bq, const float* __restrict__ bk,
        float* __restrict__ Qs, float* __restrict__ qb,
        const float* __restrict__ value2, const int* __restrict__ mask,
        float* __restrict__ P2p)
{
    const int t = threadIdx.x;

    __shared__ __align__(16) float qsh[8 * E_];   // 32 KB: 8 query rows
    __shared__ __align__(16) float Qrow[8][16];   // [bb][r]
    __shared__ int rows[NSP_];
    __shared__ int nrows;

    if (blockIdx.x < 256) {
        const int bg = blockIdx.x >> 6;        // 0..3 -> b0 = bg*8
        const int rs = blockIdx.x & 63;        // 0..63 -> rows rs*16
        const int b0 = bg * 8;
        const int R  = rs * 16;
        const int h  = rs >> 3;

        // stage 8 query rows, coalesced (32 lanes per b-row)
        {
            const int bb = t >> 5, ln = t & 31;
            const float4* src = (const float4*)(query + (size_t)(b0 + bb) * E_);
            float4* dst = (float4*)(qsh + bb * E_);
            #pragma unroll
            for (int i = 0; i < 8; ++i) dst[ln + i * 32] = src[ln + i * 32];
        }
        __syncthreads();

        // thread = (r = t>>4 of 16 rows, cl = t&15 lanes per row)
        const int r = t >> 4, cl = t & 15;
        const int row = R + r;
        const float4* wr = (const float4*)(Wq + (size_t)row * E_);
        float4 wchunk[16];
        #pragma unroll
        for (int i = 0; i < 16; ++i) wchunk[i] = wr[cl + i * 16];

        const float bqv = bq[row];
        const float4* qsh4 = (const float4*)qsh;
        #pragma unroll
        for (int bb = 0; bb < 8; ++bb) {
            float acc = 0.f;
            #pragma unroll
            for (int i = 0; i < 16; ++i) {
                float4 q = qsh4[bb * 256 + cl + i * 16];
                acc += wchunk[i].x * q.x + wchunk[i].y * q.y
                     + wchunk[i].z * q.z + wchunk[i].w * q.w;
            }
            #pragma unroll
            for (int off = 8; off; off >>= 1) acc += __shfl_xor(acc, off);
            if (cl == 0) Qrow[bb][r] = acc + bqv;
        }
        __syncthreads();

        if (t < 8) {
            float s = 0.f;
            #pragma unroll
            for (int rr = 0; rr < 16; ++rr) s += Qrow[t][rr] * bk[R + rr];
            atomicAdd(&qb[(b0 + t) * 8 + h], s);
        }
        if (t < 32) {
            const int bb = t >> 2, j = t & 3;
            ((float4*)(Qs + (size_t)(b0 + bb) * E_))[rs * 4 + j] =
                *(const float4*)&Qrow[bb][j * 4];
        }
    } else {
        // ---- v2 pooling: 32-row split; P2p[sp&7] partials
        const int pi = blockIdx.x - 256;        // [0,1024)
        const int b = pi & 31, sp = pi >> 5;
        const int e0 = t * 4;
        const int n0 = sp * NSP_;

        if (t == 0) nrows = 0;
        __syncthreads();
        if (t < NSP_) {
            if (mask[b * N_ + n0 + t]) {
                int i2 = atomicAdd(&nrows, 1);
                rows[i2] = t;
            }
        }
        __syncthreads();
        const int nr = nrows;

        float a0 = 0.f, a1 = 0.f, a2 = 0.f, a3 = 0.f;
        const float* vb = value2 + ((size_t)(b * N_ + n0)) * E_ + e0;
        #pragma unroll 4
        for (int i = 0; i < nr; ++i) {
            float4 v = *(const float4*)(vb + (size_t)rows[i] * E_);
            a0 += v.x; a1 += v.y; a2 += v.z; a3 += v.w;
        }
        float* dst = P2p + ((size_t)(sp & 7) * B_ + b) * E_ + e0;
        atomicAdd(dst + 0, a0); atomicAdd(dst + 1, a1);
        atomicAdd(dst + 2, a2); atomicAdd(dst + 3, a3);
    }
}

// ---------------------------------------------------------------------------
// k_k: qk[b,h,e] = sum_d Qs[b,h*D+d] * Wk[h*D+d,e], LDS-tiled GEMM.
// grid 256 = (h, 32-col tile); Wk read exactly once.
// ---------------------------------------------------------------------------
__global__ __launch_bounds__(256) void k_k(
        const float* __restrict__ Qs, const float* __restrict__ Wk,
        float* __restrict__ qk)
{
    const int h = blockIdx.x >> 5, ec = blockIdx.x & 31;
    const int t = threadIdx.x;

    __shared__ __align__(16) float QsL[32 * 132];   // padded, 16.9 KB
    __shared__ __align__(16) float WkL[128 * 32];   // 16 KB

    {
        const int b = t >> 3, j = t & 7;
        const float4* src = (const float4*)(Qs + (size_t)b * E_) + h * 32;
        float4* dst = (float4*)(QsL + b * 132);
        #pragma unroll
        for (int jj = 0; jj < 4; ++jj) dst[j + jj * 8] = src[j + jj * 8];
    }
    {
        #pragma unroll
        for (int jj = 0; jj < 4; ++jj) {
            const int idx = t + jj * 256;
            const int d = idx >> 3, c = idx & 7;
            ((float4*)WkL)[idx] =
                ((const float4*)(Wk + (size_t)(h * D_ + d) * E_))[ec * 8 + c];
        }
    }
    __syncthreads();

    const int b = t >> 3, eg = t & 7;
    float4 acc = make_float4(0.f, 0.f, 0.f, 0.f);
    const float* q = QsL + b * 132;
    const float4* wk4 = (const float4*)WkL;
    #pragma unroll 8
    for (int d = 0; d < D_; ++d) {
        float qd = q[d];
        float4 w = wk4[d * 8 + eg];
        acc.x += qd * w.x; acc.y += qd * w.y;
        acc.z += qd * w.z; acc.w += qd * w.w;
    }
    ((float4*)(qk + (size_t)(b * 8 + h) * E_))[ec * 8 + eg] = acc;
}

// ---------------------------------------------------------------------------
// k_main: R7 scorepool with LDS-only barriers in the subtile loop.
//   The kn prefetch now stays in flight across both barriers (the old
//   __syncthreads drained vmcnt(0) -> full HBM latency exposed 8x/block).
// grid (NT_, B_) = 1024 blocks, 256 thr, ~1 KB LDS, VGPR ~72.
// ---------------------------------------------------------------------------
__global__ __launch_bounds__(256) void k_main(
        const float* __restrict__ key, const float* __restrict__ qk,
        const float* __restrict__ qb, float* __restrict__ PPpart,
        float* __restrict__ ssum)
{
    const int tile = blockIdx.x, b = blockIdx.y;
    const int t = threadIdx.x;
    const int w = t >> 6, l = t & 63;

    __shared__ __align__(16) float part[4][4][8];   // [wave][r][h], 512 B
    __shared__ __align__(16) float sfin[4][8];      // [r][h], 128 B

    const float scale = 0.08838834764831845f;  // 1/sqrt(128)
    const float* keyb = key + ((size_t)b * N_ + (size_t)tile * TR_) * E_;
    const float qbv = (t < 32) ? qb[b * 8 + (t & 7)] : 0.f;

    float4 qkr[8];
    #pragma unroll
    for (int h = 0; h < H_; ++h)
        qkr[h] = ((const float4*)(qk + (size_t)(b * 8 + h) * E_))[t];

    float4 pacc[8];
    #pragma unroll
    for (int h = 0; h < 8; ++h) pacc[h] = make_float4(0.f, 0.f, 0.f, 0.f);

    float ts = 0.f;

    float4 kv[4];
    #pragma unroll
    for (int r = 0; r < 4; ++r)
        kv[r] = ((const float4*)(keyb + (size_t)r * E_))[t];

    for (int st = 0; st < 8; ++st) {
        // --- dots for this sub-tile's 4 rows
        #pragma unroll
        for (int r = 0; r < 4; ++r) {
            float p[8];
            #pragma unroll
            for (int h = 0; h < 8; ++h)
                p[h] = qkr[h].x * kv[r].x + qkr[h].y * kv[r].y
                     + qkr[h].z * kv[r].z + qkr[h].w * kv[r].w;
            #pragma unroll
            for (int off = 32; off; off >>= 1) {
                #pragma unroll
                for (int h = 0; h < 8; ++h)
                    p[h] += __shfl_xor(p[h], off);
            }
            if (l == 0) {
                *(float4*)&part[w][r][0] = make_float4(p[0], p[1], p[2], p[3]);
                *(float4*)&part[w][r][4] = make_float4(p[4], p[5], p[6], p[7]);
            }
        }
        // --- prefetch next sub-tile's rows (NOT drained at the barriers)
        float4 kn[4];
        if (st < 7) {
            #pragma unroll
            for (int r = 0; r < 4; ++r)
                kn[r] = ((const float4*)(keyb
                            + (size_t)((st + 1) * 4 + r) * E_))[t];
        }
        ldsbar();   // LDS-only: part[] visible; kn stays in flight
        if (t < 32) {
            const int r = t >> 3, h = t & 7;
            float s = (part[0][r][h] + part[1][r][h]
                     + part[2][r][h] + part[3][r][h] + qbv) * scale;
            sfin[r][h] = s;
            ts += s;
        }
        ldsbar();   // LDS-only: sfin visible; kn still in flight
        // --- outer product with the SAME kv registers
        #pragma unroll
        for (int r = 0; r < 4; ++r) {
            const float4 k4 = kv[r];
            const float4 sA = *(const float4*)&sfin[r][0];
            const float4 sB = *(const float4*)&sfin[r][4];
            pacc[0].x += sA.x * k4.x; pacc[0].y += sA.x * k4.y;
            pacc[0].z += sA.x * k4.z; pacc[0].w += sA.x * k4.w;
            pacc[1].x += sA.y * k4.x; pacc[1].y += sA.y * k4.y;
            pacc[1].z += sA.y * k4.z; pacc[1].w += sA.y * k4.w;
            pacc[2].x += sA.z * k4.x; pacc[2].y += sA.z * k4.y;
            pacc[2].z += sA.z * k4.z; pacc[2].w += sA.z * k4.w;
            pacc[3].x += sA.w * k4.x; pacc[3].y += sA.w * k4.y;
            pacc[3].z += sA.w * k4.z; pacc[3].w += sA.w * k4.w;
            pacc[4].x += sB.x * k4.x; pacc[4].y += sB.x * k4.y;
            pacc[4].z += sB.x * k4.z; pacc[4].w += sB.x * k4.w;
            pacc[5].x += sB.y * k4.x; pacc[5].y += sB.y * k4.y;
            pacc[5].z += sB.y * k4.z; pacc[5].w += sB.y * k4.w;
            pacc[6].x += sB.z * k4.x; pacc[6].y += sB.z * k4.y;
            pacc[6].z += sB.z * k4.z; pacc[6].w += sB.z * k4.w;
            pacc[7].x += sB.w * k4.x; pacc[7].y += sB.w * k4.y;
            pacc[7].z += sB.w * k4.z; pacc[7].w += sB.w * k4.w;
        }
        #pragma unroll
        for (int r = 0; r < 4; ++r) kv[r] = kn[r];   // vmcnt wait lands here
    }

    if (t < 32) {
        float v = ts;
        v += __shfl_xor(v, 8);
        v += __shfl_xor(v, 16);
        if (l < 8) atomicAdd(&ssum[b * 8 + l], v);
    }

    #pragma unroll
    for (int h = 0; h < 8; ++h) {
        ((float4*)(PPpart
            + (((size_t)(b * H_ + h)) * NT_ + tile) * E_))[t] = pacc[h];
    }
}

// ---------------------------------------------------------------------------
// k_tail (R8-proven): per bh, 512 threads.
//  stage1: pooled = sum_tl PPpart[bh,tl,:] (2 halves); pool2 = sum P2p[8]
//  stage2: attA/attV[d] = pooled/pool2 · Wv_row(h*D+d), 8 waves x 16 d
//  stage3: epilogue (hv, alphac, v2a, out)
// ---------------------------------------------------------------------------
__global__ __launch_bounds__(512) void k_tail(
        const float* __restrict__ PPpart, const float* __restrict__ P2p,
        const float* __restrict__ ssumg, const int* __restrict__ mask,
        const float* __restrict__ Wv, const float* __restrict__ bv,
        const float* __restrict__ Wb, const float* __restrict__ bb,
        const float* __restrict__ Wl2, const float* __restrict__ bl2,
        const float* __restrict__ value1, float* __restrict__ out)
{
    const int bh = blockIdx.x, b = bh >> 3, h = bh & 7;
    const int t = threadIdx.x;
    const int l = t & 63, w = t >> 6;       // 8 waves
    const int rg = l >> 4, cl = l & 15;     // 4 row-groups x 16 lanes

    __shared__ __align__(16) float ph[2][E_];
    __shared__ __align__(16) float pooled[E_];
    __shared__ __align__(16) float pool2[E_];
    __shared__ float attA_s[D_];
    __shared__ float attV_s[D_];
    __shared__ float att[D_];
    __shared__ float hv[MID_];
    __shared__ float red2[2];
    __shared__ float cnt_s;

    {
        const int c4 = t & 255, half = t >> 8;
        const float4* pp = (const float4*)(PPpart + (size_t)bh * NT_ * E_);
        float4 s = make_float4(0.f, 0.f, 0.f, 0.f);
        #pragma unroll 4
        for (int j = 0; j < 16; ++j) {
            float4 v = pp[(half * 16 + j) * 256 + c4];
            s.x += v.x; s.y += v.y; s.z += v.z; s.w += v.w;
        }
        ((float4*)&ph[half][0])[c4] = s;
    }
    __syncthreads();
    if (t < 256) {
        float4 p0 = ((const float4*)&ph[0][0])[t];
        float4 p1 = ((const float4*)&ph[1][0])[t];
        ((float4*)pooled)[t] = make_float4(p0.x + p1.x, p0.y + p1.y,
                                           p0.z + p1.z, p0.w + p1.w);
        float4 q = make_float4(0.f, 0.f, 0.f, 0.f);
        #pragma unroll
        for (int k2 = 0; k2 < 8; ++k2) {
            float4 v = ((const float4*)(P2p + ((size_t)k2 * B_ + b) * E_))[t];
            q.x += v.x; q.y += v.y; q.z += v.z; q.w += v.w;
        }
        ((float4*)pool2)[t] = q;
    }
    __syncthreads();

    const float4* pooled4 = (const float4*)pooled;
    const float4* pool24  = (const float4*)pool2;
    #pragma unroll
    for (int p = 0; p < 4; ++p) {
        const int d = p * 32 + w * 4 + rg;
        const float4* wvr = (const float4*)(Wv + (size_t)(h * D_ + d) * E_);
        float pA = 0.f, pV = 0.f;
        #pragma unroll 4
        for (int i = 0; i < 16; ++i) {
            float4 wv4 = wvr[cl + i * 16];
            float4 pa = pooled4[cl + i * 16];
            float4 pb = pool24[cl + i * 16];
            pA += wv4.x * pa.x + wv4.y * pa.y + wv4.z * pa.z + wv4.w * pa.w;
            pV += wv4.x * pb.x + wv4.y * pb.y + wv4.z * pb.z + wv4.w * pb.w;
        }
        #pragma unroll
        for (int off = 8; off; off >>= 1) {
            pA += __shfl_xor(pA, off);
            pV += __shfl_xor(pV, off);
        }
        if (cl == 0) { attA_s[d] = pA; attV_s[d] = pV; }
    }
    __syncthreads();

    if (t < 128) {
        int ci = 0;
        #pragma unroll
        for (int i = 0; i < 8; ++i) ci += mask[b * N_ + t + i * 128];
        float cf = (float)ci;
        #pragma unroll
        for (int off = 32; off; off >>= 1) cf += __shfl_down(cf, off);
        if ((t & 63) == 0) red2[t >> 6] = cf;
        const float ss = ssumg[bh];
        att[t] = attA_s[t] + ss * bv[h * D_ + t];
    }
    __syncthreads();
    if (t == 0) cnt_s = red2[0] + red2[1];
    if (t < MID_) {
        float a = bb[t];
        #pragma unroll 4
        for (int d2 = 0; d2 < D_; ++d2) a += att[d2] * Wb[t * D_ + d2];
        hv[t] = fmaxf(a, 0.f);
    }
    __syncthreads();
    if (t < 128) {
        float z = bl2[t];
        #pragma unroll
        for (int m = 0; m < MID_; ++m) z += hv[m] * Wl2[t * MID_ + m];
        float alphac = 1.f / (1.f + expf(-z));
        const float bvd = bv[h * D_ + t];
        float v2a = attV_s[t] / cnt_s + bvd;
        out[(size_t)b * E_ + h * D_ + t] =
            value1[(size_t)b * E_ + h * D_ + t] * v2a * alphac;
    }
}

// ---------------------------------------------------------------------------
extern "C" void kernel_launch(void* const* d_in, const int* in_sizes, int n_in,
                              void* d_out, int out_size, void* d_ws, size_t ws_size,
                              hipStream_t stream)
{
    const float* query  = (const float*)d_in[0];
    const float* key    = (const float*)d_in[1];
    const int*   mask   = (const int*)d_in[2];
    const float* value1 = (const float*)d_in[3];
    const float* value2 = (const float*)d_in[4];
    const float* Wq  = (const float*)d_in[5];
    const float* bq  = (const float*)d_in[6];
    const float* Wk  = (const float*)d_in[7];
    const float* bk  = (const float*)d_in[8];
    const float* Wv  = (const float*)d_in[9];
    const float* bv  = (const float*)d_in[10];
    const float* Wb  = (const float*)d_in[11];
    const float* bb  = (const float*)d_in[12];
    // d_in[13] = Wl, d_in[14] = bl: eliminated (softmax of uniform = mask/cnt)
    const float* Wl2 = (const float*)d_in[15];
    const float* bl2 = (const float*)d_in[16];
    float* out = (float*)d_out;

    // workspace layout (bytes), ~35 MB
    char* ws = (char*)d_ws;
    const size_t SZ_PPP = (size_t)B_ * H_ * NT_ * E_ * 4;     // PPpart: 32 MB
    const size_t SZ_P2P = (size_t)8 * B_ * E_ * 4;            // P2p: 1 MB
    const size_t OFF_P2P = SZ_PPP;
    const size_t OFF_SS  = OFF_P2P + SZ_P2P;                  // ssum: 1 KB
    const size_t OFF_QB  = OFF_SS + 1024;                     // qb: 1 KB
    const size_t OFF_QS  = OFF_QB + 1024;                     // Qs: 128 KB
    const size_t OFF_QK  = OFF_QS + (size_t)B_ * E_ * 4;      // qk: 1 MB
    float* PPpart = (float*)(ws);
    float* P2p    = (float*)(ws + OFF_P2P);
    float* ssum   = (float*)(ws + OFF_SS);
    float* qb     = (float*)(ws + OFF_QB);
    float* Qs     = (float*)(ws + OFF_QS);
    float* qk     = (float*)(ws + OFF_QK);

    // zero atomic-accumulated regions: P2p + ssum + qb (contiguous)
    hipMemsetAsync(ws + OFF_P2P, 0, SZ_P2P + 2048, stream);

    hipLaunchKernelGGL(k_q, dim3(256 + NT_ * B_), dim3(256), 0, stream,
                       query, Wq, bq, bk, Qs, qb, value2, mask, P2p);
    hipLaunchKernelGGL(k_k, dim3(256), dim3(256), 0, stream,
                       Qs, Wk, qk);
    hipLaunchKernelGGL(k_main, dim3(NT_, B_), dim3(256), 0, stream,
                       key, qk, qb, PPpart, ssum);
    hipLaunchKernelGGL(k_tail, dim3(B_ * H_), dim3(512), 0, stream,
                       PPpart, P2p, ssum, mask, Wv, bv, Wb, bb, Wl2, bl2,
                       value1, out);
}